// Round 2
// baseline (105.858 us; speedup 1.0000x reference)
//
#include <hip/hip_runtime.h>

#define NE     100000
#define NR     64
#define DIM    16
#define NHOP   2
#define NMEM   32
#define NNODES 16384

#define WPITCH 20                 // W staging pitch in floats (80 B)

typedef __attribute__((ext_vector_type(2))) _Float16 half2_t;

static __device__ __forceinline__ half2_t as_h2(unsigned u) {
    union { unsigned i; half2_t h; } c; c.i = u; return c.h;
}
static __device__ __forceinline__ float qdot2(unsigned u, unsigned ip, float q) {
#if __has_builtin(__builtin_amdgcn_fdot2)
    return __builtin_amdgcn_fdot2(as_h2(u), as_h2(ip), q, false);
#else
    half2_t a = as_h2(u), b = as_h2(ip);
    return q + (float)a.x * (float)b.x + (float)a.y * (float)b.y;
#endif
}
static __device__ __forceinline__ float dpp_sum16(float v) {
    union { int i; float f; } a, b;
    a.f = v;
    b.i = __builtin_amdgcn_update_dpp(0, a.i, 0xB1,  0xf, 0xf, true); a.f += b.f; // quad_perm [1,0,3,2]
    b.i = __builtin_amdgcn_update_dpp(0, a.i, 0x4E,  0xf, 0xf, true); a.f += b.f; // quad_perm [2,3,0,1]
    b.i = __builtin_amdgcn_update_dpp(0, a.i, 0x124, 0xf, 0xf, true); a.f += b.f; // row_ror:4
    b.i = __builtin_amdgcn_update_dpp(0, a.i, 0x128, 0xf, 0xf, true); a.f += b.f; // row_ror:8
    return a.f;
}
static __device__ __forceinline__ float bcast(float v, int l) {
    return __int_as_float(__builtin_amdgcn_readlane(__float_as_int(v), l));
}
static __device__ __forceinline__ unsigned pack2h(float a, float b) {
    union { _Float16 h[2]; unsigned u; } c;
    c.h[0] = (_Float16)a; c.h[1] = (_Float16)b;
    return c.u;
}

// Single fused kernel: no prep pass, no workspace.
//  - Entities gathered directly as fp32 (6.4 MB table, L2/L3-resident).
//  - Relation table converted fp32 -> f16 + transposed + XOR-swizzled into
//    LDS by each block (64 KB L2-resident reads; layout identical to the
//    old pre-swizzled rtg, so the compute loop is unchanged and measured
//    0 bank conflicts).
// 512 threads = 8 nodes/block: 2048 blocks, 2 blocks/CU at 16 waves/CU so
// one block computes while the other stages.
extern "C" __global__ void __launch_bounds__(512, 4)
ripple_kernel(const int* __restrict__ nodes,
              const int* __restrict__ mh,
              const int* __restrict__ mr,
              const int* __restrict__ mt,
              const float* __restrict__ ent,
              const float* __restrict__ rel,
              const float* __restrict__ W,
              float* __restrict__ out)
{
    __shared__ __align__(16) unsigned short rt[NR * 256];   // 32768 B
    __shared__ __align__(16) float ws[DIM * WPITCH];        // 1280 B

    const int tid  = threadIdx.x;
    const int lane = tid & 63;
    const int wid  = tid >> 6;    // 0..7
    const int g    = lane >> 4;   // mem-group 0..3 -> owns mems [8g, 8g+8)
    const int e    = lane & 15;   // dim index
    const int n    = blockIdx.x * 8 + wid;

    // ---- Round 1: all index loads (both hops) — issue first ----
    const int ib0 = 0 * (NNODES * NMEM) + n * NMEM + g * 8;
    const int ib1 = 1 * (NNODES * NMEM) + n * NMEM + g * 8;
    int hi0[8], ri0[8], ti0[8], hi1[8], ri1[8], ti1[8];
    {
        const int4* p;
        p = (const int4*)(mh + ib0); *(int4*)&hi0[0] = p[0]; *(int4*)&hi0[4] = p[1];
        p = (const int4*)(mr + ib0); *(int4*)&ri0[0] = p[0]; *(int4*)&ri0[4] = p[1];
        p = (const int4*)(mt + ib0); *(int4*)&ti0[0] = p[0]; *(int4*)&ti0[4] = p[1];
        p = (const int4*)(mh + ib1); *(int4*)&hi1[0] = p[0]; *(int4*)&hi1[4] = p[1];
        p = (const int4*)(mr + ib1); *(int4*)&ri1[0] = p[0]; *(int4*)&ri1[4] = p[1];
        p = (const int4*)(mt + ib1); *(int4*)&ti1[0] = p[0]; *(int4*)&ti1[4] = p[1];
    }
    const int nd = nodes[n];

    // ---- Relation staging (fused prep): fp32 -> f16, transposed+swizzled.
    // Thread owns (r, dq, e): element (d=4dq+i, e) of relation r lands at
    // ushort rt[r*256 + e*16 + phys*4 + i], phys = (dq + e/4) & 3 — one
    // contiguous 8 B ds_write per thread per iteration. Loads: 16 lanes of
    // consecutive e read 64 B contiguous per d-row (coalesced).
    {
        #pragma unroll
        for (int it = 0; it < 8; ++it) {
            const int idx = it * 512 + tid;       // 0..4095 = 64r * 4dq * 16e
            const int e0  = idx & 15;
            const int dq  = (idx >> 4) & 3;
            const int r   = idx >> 6;
            const float* s = rel + r * 256 + dq * 64 + e0;
            const float f0 = s[0], f1 = s[16], f2 = s[32], f3 = s[48];
            const int phys = (dq + (e0 >> 2)) & 3;
            uint2 pk;
            pk.x = pack2h(f0, f1);
            pk.y = pack2h(f2, f3);
            *(uint2*)((char*)rt + (r << 9) + (e0 << 5) + (phys << 3)) = pk;
        }
        if (tid < 256) ws[(tid >> 4) * WPITCH + (tid & 15)] = W[tid];
    }

    // ---- Round 2: all entity gathers (both hops), fp32, burst-issued ----
    float item = ent[nd * DIM + e];
    float hv0[8], tv0[8], hv1[8], tv1[8];
    #pragma unroll
    for (int it = 0; it < 8; ++it) {
        hv0[it] = ent[hi0[it] * DIM + e];
        tv0[it] = ent[ti0[it] * DIM + e];
        hv1[it] = ent[hi1[it] * DIM + e];
        tv1[it] = ent[ti1[it] * DIM + e];
    }

    __syncthreads();   // staging writes + W visible; gathers awaited at use

    // Per-lane byte offsets into a relation's row for logical chunk j (swizzled)
    int voff[4];
    {
        const int s = e >> 2;
        #pragma unroll
        for (int j = 0; j < 4; ++j)
            voff[j] = e * 32 + (((j + s) & 3) << 3);
    }

    float out_acc = 0.f;

    #pragma unroll
    for (int hop = 0; hop < NHOP; ++hop) {
        const int*   ri = hop ? ri1 : ri0;
        const float* hv = hop ? hv1 : hv0;
        const float* tv = hop ? tv1 : tv0;

        // item vector -> 8 packed f16 pairs, wave-uniform (SGPRs)
        unsigned ip[8];
        #pragma unroll
        for (int j = 0; j < 8; ++j)
            ip[j] = pack2h(bcast(item, 2 * j), bcast(item, 2 * j + 1));

        // online softmax over the 8 owned memories
        float Z = 0.f, o = 0.f;
        #pragma unroll
        for (int it = 0; it < 8; ++it) {
            const char* rbase = (const char*)rt + (ri[it] << 9);
            float q = 0.f;
            #pragma unroll
            for (int j = 0; j < 4; ++j) {
                uint2 u = *(const uint2*)(rbase + voff[j]);
                q = qdot2(u.x, ip[2 * j + 0], q);
                q = qdot2(u.y, ip[2 * j + 1], q);
            }
            float sc = dpp_sum16(q * hv[it]);   // item . (R @ h)
            float ex = __expf(sc);              // scores small: no max pass
            Z += ex;
            o += ex * tv[it];
        }
        Z += __shfl_xor(Z, 16);
        Z += __shfl_xor(Z, 32);
        o += __shfl_xor(o, 16);
        o += __shfl_xor(o, 32);
        o *= 1.f / Z;

        out_acc += (hop == 0) ? 2.f * o : o;    // faithful: result = o1 + 2*o0

        // item = (item + o) @ W.T ; W row e from LDS
        const float v = item + o;
        float nit = 0.f;
        const float4* wr = (const float4*)&ws[e * WPITCH];
        #pragma unroll
        for (int j = 0; j < 4; ++j) {
            float4 w = wr[j];
            nit += w.x * bcast(v, 4 * j + 0) + w.y * bcast(v, 4 * j + 1)
                 + w.z * bcast(v, 4 * j + 2) + w.w * bcast(v, 4 * j + 3);
        }
        item = nit;
    }

    if (lane < 16) out[n * DIM + e] = out_acc;
}

extern "C" void kernel_launch(void* const* d_in, const int* in_sizes, int n_in,
                              void* d_out, int out_size, void* d_ws, size_t ws_size,
                              hipStream_t stream) {
    const int*   nodes = (const int*)d_in[0];
    const int*   mh    = (const int*)d_in[1];
    const int*   mr    = (const int*)d_in[2];
    const int*   mt    = (const int*)d_in[3];
    const float* ent   = (const float*)d_in[4];
    const float* rel   = (const float*)d_in[5];
    const float* W     = (const float*)d_in[6];
    float*       out   = (float*)d_out;

    (void)d_ws; (void)ws_size;   // single fused launch; no workspace, no prep

    dim3 grid(NNODES / 8);   // 1 wave per node, 8 nodes per 512-thread block
    dim3 block(512);
    ripple_kernel<<<grid, block, 0, stream>>>(nodes, mh, mr, mt, ent, rel, W, out);
}

// Round 3
// 103.677 us; speedup vs baseline: 1.0210x; 1.0210x over previous
//
#include <hip/hip_runtime.h>

#define NE     100000
#define NR     64
#define DIM    16
#define NHOP   2
#define NMEM   32
#define NNODES 16384

#define WPITCH 20                 // W staging pitch in floats (80 B)
#define ET_BYTES (NE * DIM * 2)   // 3.2 MB f16 entity table in d_ws
#define NB_ET  ((NE * DIM / 4 + 255) / 256)   // 1563 blocks for et conversion

#define NBLK  1024                // resident set: 4 blocks/CU x 256 CU
#define ITERS (NNODES / (NBLK * 4))   // 4 node-groups per block, rt staged once

typedef __attribute__((ext_vector_type(2))) _Float16 half2_t;

static __device__ __forceinline__ half2_t as_h2(unsigned u) {
    union { unsigned i; half2_t h; } c; c.i = u; return c.h;
}
static __device__ __forceinline__ float qdot2(unsigned u, unsigned ip, float q) {
#if __has_builtin(__builtin_amdgcn_fdot2)
    return __builtin_amdgcn_fdot2(as_h2(u), as_h2(ip), q, false);
#else
    half2_t a = as_h2(u), b = as_h2(ip);
    return q + (float)a.x * (float)b.x + (float)a.y * (float)b.y;
#endif
}
static __device__ __forceinline__ float dpp_sum16(float v) {
    union { int i; float f; } a, b;
    a.f = v;
    b.i = __builtin_amdgcn_update_dpp(0, a.i, 0xB1,  0xf, 0xf, true); a.f += b.f; // quad_perm [1,0,3,2]
    b.i = __builtin_amdgcn_update_dpp(0, a.i, 0x4E,  0xf, 0xf, true); a.f += b.f; // quad_perm [2,3,0,1]
    b.i = __builtin_amdgcn_update_dpp(0, a.i, 0x124, 0xf, 0xf, true); a.f += b.f; // row_ror:4
    b.i = __builtin_amdgcn_update_dpp(0, a.i, 0x128, 0xf, 0xf, true); a.f += b.f; // row_ror:8
    return a.f;
}
static __device__ __forceinline__ float bcast(float v, int l) {
    return __int_as_float(__builtin_amdgcn_readlane(__float_as_int(v), l));
}
static __device__ __forceinline__ unsigned short f2h(float f) {
    union { _Float16 h; unsigned short s; } c; c.h = (_Float16)f; return c.s;
}
static __device__ __forceinline__ unsigned pack2h(float a, float b) {
    union { _Float16 h[2]; unsigned u; } c;
    c.h[0] = (_Float16)a; c.h[1] = (_Float16)b;
    return c.u;
}

// ---- Prep: (a) entity_emb fp32 -> f16 table (3.2 MB: L2-resident for the
// random gathers); (b) relation_emb fp32 -> f16 TRANSPOSED + XOR-swizzled
// table (exact byte image the main kernel copies flat into LDS; measured
// 0 bank conflicts).
extern "C" __global__ void __launch_bounds__(256)
prep_kernel(const float* __restrict__ ent, const float* __restrict__ rel,
            _Float16* __restrict__ et, unsigned short* __restrict__ rtg, int n4)
{
    const int b = blockIdx.x, tid = threadIdx.x;
    if (b < NB_ET) {
        int i = b * 256 + tid;
        if (i < n4) {
            float4 v = ((const float4*)ent)[i];
            union { _Float16 h[4]; unsigned long long u; } c;
            c.h[0] = (_Float16)v.x; c.h[1] = (_Float16)v.y;
            c.h[2] = (_Float16)v.z; c.h[3] = (_Float16)v.w;
            *(unsigned long long*)(et + 4 * (long long)i) = c.u;
        }
    } else {
        int j = (b - NB_ET) * 256 + tid;          // 0..1023
        const float4* rel4 = (const float4*)rel;
        #pragma unroll
        for (int k = 0; k < 4; ++k) {
            int vidx = k * 1024 + j;              // 4096 float4s total
            float4 v = rel4[vidx];
            int k0 = vidx * 4;
            int r  = k0 >> 8;
            int kk = k0 & 255;
            int d  = kk >> 4;
            int e0 = kk & 15;
            int phys = ((d >> 2) + (e0 >> 2)) & 3;
            unsigned short* p = &rtg[r * 256 + e0 * 16 + phys * 4 + (d & 3)];
            p[0]  = f2h(v.x);
            p[16] = f2h(v.y);
            p[32] = f2h(v.z);
            p[48] = f2h(v.w);
        }
    }
}

// R0 structure + block-level rt reuse: 1024 blocks (exactly the 4-block/CU
// resident set), each stages the 32 KB relation table ONCE and then loops
// over 4 node-groups. Staging L2 traffic: 128 MB -> 32 MB; barriers
// 4096 -> 1024. Per-iteration compute identical to the proven R0 loop.
extern "C" __global__ void __launch_bounds__(256, 4)
ripple_kernel(const int* __restrict__ nodes,
              const int* __restrict__ mh,
              const int* __restrict__ mr,
              const int* __restrict__ mt,
              const _Float16* __restrict__ et,
              const unsigned short* __restrict__ rtg,
              const float* __restrict__ W,
              float* __restrict__ out)
{
    __shared__ __align__(16) unsigned short rt[NR * 256];   // 32768 B
    __shared__ __align__(16) float ws[DIM * WPITCH];        // 1280 B

    const int tid  = threadIdx.x;
    const int lane = tid & 63;
    const int wid  = tid >> 6;    // 0..3
    const int g    = lane >> 4;   // mem-group 0..3 -> owns mems [8g, 8g+8)
    const int e    = lane & 15;   // dim index

    // ---- Stage rt + W once per block ----
    {
        float4 stg[8];
        const float4* src = (const float4*)rtg;
        #pragma unroll
        for (int i = 0; i < 8; ++i) stg[i] = src[i * 256 + tid];
        const float wv = W[tid];
        float4* dst = (float4*)rt;
        #pragma unroll
        for (int i = 0; i < 8; ++i) dst[i * 256 + tid] = stg[i];
        ws[(tid >> 4) * WPITCH + (tid & 15)] = wv;
    }
    __syncthreads();

    // Per-lane byte offsets into a relation's row for logical chunk j (swizzled)
    int voff[4];
    {
        const int s = e >> 2;
        #pragma unroll
        for (int j = 0; j < 4; ++j)
            voff[j] = e * 32 + (((j + s) & 3) << 3);
    }

    #pragma unroll 1
    for (int iter = 0; iter < ITERS; ++iter) {
        const int n = blockIdx.x * 4 + wid + iter * (NBLK * 4);

        // ---- Index loads (both hops) — burst-issued ----
        const int ib0 = 0 * (NNODES * NMEM) + n * NMEM + g * 8;
        const int ib1 = 1 * (NNODES * NMEM) + n * NMEM + g * 8;
        int hi0[8], ri0[8], ti0[8], hi1[8], ri1[8], ti1[8];
        {
            const int4* p;
            p = (const int4*)(mh + ib0); *(int4*)&hi0[0] = p[0]; *(int4*)&hi0[4] = p[1];
            p = (const int4*)(mr + ib0); *(int4*)&ri0[0] = p[0]; *(int4*)&ri0[4] = p[1];
            p = (const int4*)(mt + ib0); *(int4*)&ti0[0] = p[0]; *(int4*)&ti0[4] = p[1];
            p = (const int4*)(mh + ib1); *(int4*)&hi1[0] = p[0]; *(int4*)&hi1[4] = p[1];
            p = (const int4*)(mr + ib1); *(int4*)&ri1[0] = p[0]; *(int4*)&ri1[4] = p[1];
            p = (const int4*)(mt + ib1); *(int4*)&ti1[0] = p[0]; *(int4*)&ti1[4] = p[1];
        }
        const int nd = nodes[n];

        // ---- Entity gathers (both hops), f16 table, burst-issued ----
        float item = (float)et[nd * DIM + e];
        float hv0[8], tv0[8], hv1[8], tv1[8];
        #pragma unroll
        for (int it = 0; it < 8; ++it) {
            hv0[it] = (float)et[hi0[it] * DIM + e];
            tv0[it] = (float)et[ti0[it] * DIM + e];
            hv1[it] = (float)et[hi1[it] * DIM + e];
            tv1[it] = (float)et[ti1[it] * DIM + e];
        }

        float out_acc = 0.f;

        #pragma unroll
        for (int hop = 0; hop < NHOP; ++hop) {
            const int*   ri = hop ? ri1 : ri0;
            const float* hv = hop ? hv1 : hv0;
            const float* tv = hop ? tv1 : tv0;

            // item vector -> 8 packed f16 pairs, wave-uniform (SGPRs)
            unsigned ip[8];
            #pragma unroll
            for (int j = 0; j < 8; ++j)
                ip[j] = pack2h(bcast(item, 2 * j), bcast(item, 2 * j + 1));

            // online softmax over the 8 owned memories
            float Z = 0.f, o = 0.f;
            #pragma unroll
            for (int it = 0; it < 8; ++it) {
                const char* rbase = (const char*)rt + (ri[it] << 9);
                float q = 0.f;
                #pragma unroll
                for (int j = 0; j < 4; ++j) {
                    uint2 u = *(const uint2*)(rbase + voff[j]);
                    q = qdot2(u.x, ip[2 * j + 0], q);
                    q = qdot2(u.y, ip[2 * j + 1], q);
                }
                float sc = dpp_sum16(q * hv[it]);   // item . (R @ h)
                float ex = __expf(sc);              // scores small: no max pass
                Z += ex;
                o += ex * tv[it];
            }
            Z += __shfl_xor(Z, 16);
            Z += __shfl_xor(Z, 32);
            o += __shfl_xor(o, 16);
            o += __shfl_xor(o, 32);
            o *= 1.f / Z;

            out_acc += (hop == 0) ? 2.f * o : o;    // faithful: result = o1 + 2*o0

            // item = (item + o) @ W.T ; W row e from LDS
            const float v = item + o;
            float nit = 0.f;
            const float4* wr = (const float4*)&ws[e * WPITCH];
            #pragma unroll
            for (int j = 0; j < 4; ++j) {
                float4 w = wr[j];
                nit += w.x * bcast(v, 4 * j + 0) + w.y * bcast(v, 4 * j + 1)
                     + w.z * bcast(v, 4 * j + 2) + w.w * bcast(v, 4 * j + 3);
            }
            item = nit;
        }

        if (lane < 16) out[n * DIM + e] = out_acc;
    }
}

extern "C" void kernel_launch(void* const* d_in, const int* in_sizes, int n_in,
                              void* d_out, int out_size, void* d_ws, size_t ws_size,
                              hipStream_t stream) {
    const int*   nodes = (const int*)d_in[0];
    const int*   mh    = (const int*)d_in[1];
    const int*   mr    = (const int*)d_in[2];
    const int*   mt    = (const int*)d_in[3];
    const float* ent   = (const float*)d_in[4];
    const float* rel   = (const float*)d_in[5];
    const float* W     = (const float*)d_in[6];
    float*       out   = (float*)d_out;

    _Float16*       et  = (_Float16*)d_ws;                           // 3.2 MB
    unsigned short* rtg = (unsigned short*)((char*)d_ws + ET_BYTES); // 32 KB

    const int n4 = NE * DIM / 4;              // 400000 float4s
    prep_kernel<<<NB_ET + 4, 256, 0, stream>>>(ent, rel, et, rtg, n4);

    dim3 grid(NBLK);    // 1024 blocks: resident set, each loops 4 node-groups
    dim3 block(256);
    ripple_kernel<<<grid, block, 0, stream>>>(nodes, mh, mr, mt, et, rtg, W, out);
}

// Round 4
// 101.204 us; speedup vs baseline: 1.0460x; 1.0244x over previous
//
#include <hip/hip_runtime.h>

#define NE     100000
#define NR     64
#define DIM    16
#define NHOP   2
#define NMEM   32
#define NNODES 16384

#define WPITCH 20                 // W staging pitch in floats (80 B)
#define ET_BYTES (NE * DIM * 2)   // 3.2 MB f16 entity table in d_ws
#define NB_ET  ((NE * DIM / 4 + 255) / 256)   // 1563 blocks for et conversion

typedef __attribute__((ext_vector_type(2))) _Float16 half2_t;

static __device__ __forceinline__ half2_t as_h2(unsigned u) {
    union { unsigned i; half2_t h; } c; c.i = u; return c.h;
}
static __device__ __forceinline__ float qdot2(unsigned u, unsigned ip, float q) {
#if __has_builtin(__builtin_amdgcn_fdot2)
    return __builtin_amdgcn_fdot2(as_h2(u), as_h2(ip), q, false);
#else
    half2_t a = as_h2(u), b = as_h2(ip);
    return q + (float)a.x * (float)b.x + (float)a.y * (float)b.y;
#endif
}
static __device__ __forceinline__ float dpp_sum16(float v) {
    union { int i; float f; } a, b;
    a.f = v;
    b.i = __builtin_amdgcn_update_dpp(0, a.i, 0xB1,  0xf, 0xf, true); a.f += b.f; // quad_perm [1,0,3,2]
    b.i = __builtin_amdgcn_update_dpp(0, a.i, 0x4E,  0xf, 0xf, true); a.f += b.f; // quad_perm [2,3,0,1]
    b.i = __builtin_amdgcn_update_dpp(0, a.i, 0x124, 0xf, 0xf, true); a.f += b.f; // row_ror:4
    b.i = __builtin_amdgcn_update_dpp(0, a.i, 0x128, 0xf, 0xf, true); a.f += b.f; // row_ror:8
    return a.f;
}
static __device__ __forceinline__ float bcast(float v, int l) {
    return __int_as_float(__builtin_amdgcn_readlane(__float_as_int(v), l));
}
static __device__ __forceinline__ unsigned short f2h(float f) {
    union { _Float16 h; unsigned short s; } c; c.h = (_Float16)f; return c.s;
}
static __device__ __forceinline__ unsigned pack2h(float a, float b) {
    union { _Float16 h[2]; unsigned u; } c;
    c.h[0] = (_Float16)a; c.h[1] = (_Float16)b;
    return c.u;
}

// ---- Prep: (a) entity_emb fp32 -> f16 table; (b) relation_emb fp32 ->
// f16 TRANSPOSED + XOR-swizzled table (exact byte layout the main kernel
// copies flat into LDS; swizzle details as R2/R7, measured 0 conflicts).
extern "C" __global__ void __launch_bounds__(256)
prep_kernel(const float* __restrict__ ent, const float* __restrict__ rel,
            _Float16* __restrict__ et, unsigned short* __restrict__ rtg, int n4)
{
    const int b = blockIdx.x, tid = threadIdx.x;
    if (b < NB_ET) {
        int i = b * 256 + tid;
        if (i < n4) {
            float4 v = ((const float4*)ent)[i];
            union { _Float16 h[4]; unsigned long long u; } c;
            c.h[0] = (_Float16)v.x; c.h[1] = (_Float16)v.y;
            c.h[2] = (_Float16)v.z; c.h[3] = (_Float16)v.w;
            *(unsigned long long*)(et + 4 * (long long)i) = c.u;
        }
    } else {
        int j = (b - NB_ET) * 256 + tid;          // 0..1023
        const float4* rel4 = (const float4*)rel;
        #pragma unroll
        for (int k = 0; k < 4; ++k) {
            int vidx = k * 1024 + j;              // 4096 float4s total
            float4 v = rel4[vidx];
            int k0 = vidx * 4;
            int r  = k0 >> 8;
            int kk = k0 & 255;
            int d  = kk >> 4;
            int e0 = kk & 15;
            int phys = ((d >> 2) + (e0 >> 2)) & 3;
            unsigned short* p = &rtg[r * 256 + e0 * 16 + phys * 4 + (d & 3)];
            p[0]  = f2h(v.x);
            p[16] = f2h(v.y);
            p[32] = f2h(v.z);
            p[48] = f2h(v.w);
        }
    }
}

extern "C" __global__ void __launch_bounds__(256, 4)
ripple_kernel(const int* __restrict__ nodes,
              const int* __restrict__ mh,
              const int* __restrict__ mr,
              const int* __restrict__ mt,
              const _Float16* __restrict__ et,
              const unsigned short* __restrict__ rtg,
              const float* __restrict__ W,
              float* __restrict__ out)
{
    __shared__ __align__(16) unsigned short rt[NR * 256];   // 32768 B
    __shared__ __align__(16) float ws[DIM * WPITCH];        // 1280 B

    const int tid  = threadIdx.x;
    const int lane = tid & 63;
    const int wid  = tid >> 6;
    const int g    = lane >> 4;   // mem-group 0..3 -> owns mems [8g, 8g+8)
    const int e    = lane & 15;   // dim index
    const int n    = blockIdx.x * 4 + wid;

    // ---- Round 1: all index loads (both hops) — issue first ----
    const int ib0 = 0 * (NNODES * NMEM) + n * NMEM + g * 8;
    const int ib1 = 1 * (NNODES * NMEM) + n * NMEM + g * 8;
    int hi0[8], ri0[8], ti0[8], hi1[8], ri1[8], ti1[8];
    {
        const int4* p;
        p = (const int4*)(mh + ib0); *(int4*)&hi0[0] = p[0]; *(int4*)&hi0[4] = p[1];
        p = (const int4*)(mr + ib0); *(int4*)&ri0[0] = p[0]; *(int4*)&ri0[4] = p[1];
        p = (const int4*)(mt + ib0); *(int4*)&ti0[0] = p[0]; *(int4*)&ti0[4] = p[1];
        p = (const int4*)(mh + ib1); *(int4*)&hi1[0] = p[0]; *(int4*)&hi1[4] = p[1];
        p = (const int4*)(mr + ib1); *(int4*)&ri1[0] = p[0]; *(int4*)&ri1[4] = p[1];
        p = (const int4*)(mt + ib1); *(int4*)&ti1[0] = p[0]; *(int4*)&ti1[4] = p[1];
    }
    const int nd = nodes[n];

    // ---- Independent staging loads (issue while indices are in flight) ----
    float4 stg[8];
    {
        const float4* src = (const float4*)rtg;
        #pragma unroll
        for (int i = 0; i < 8; ++i) stg[i] = src[i * 256 + tid];
    }
    const float wv = W[tid];

    // ---- Round 2: all entity gathers (both hops), burst-issued ----
    float item = (float)et[nd * DIM + e];
    float hv0[8], tv0[8], hv1[8], tv1[8];
    #pragma unroll
    for (int it = 0; it < 8; ++it) {
        hv0[it] = (float)et[hi0[it] * DIM + e];
        tv0[it] = (float)et[ti0[it] * DIM + e];
        hv1[it] = (float)et[hi1[it] * DIM + e];
        tv1[it] = (float)et[ti1[it] * DIM + e];
    }

    // ---- LDS fill (vmcnt FIFO: waits staging loads, NOT the gathers) ----
    {
        float4* dst = (float4*)rt;
        #pragma unroll
        for (int i = 0; i < 8; ++i) dst[i * 256 + tid] = stg[i];
        ws[(tid >> 4) * WPITCH + (tid & 15)] = wv;
    }
    __syncthreads();

    // Per-lane byte offsets into a relation's row for logical chunk j (swizzled)
    int voff[4];
    {
        const int s = e >> 2;
        #pragma unroll
        for (int j = 0; j < 4; ++j)
            voff[j] = e * 32 + (((j + s) & 3) << 3);
    }

    float out_acc = 0.f;

    #pragma unroll
    for (int hop = 0; hop < NHOP; ++hop) {
        const int*   ri = hop ? ri1 : ri0;
        const float* hv = hop ? hv1 : hv0;
        const float* tv = hop ? tv1 : tv0;

        // item vector -> 8 packed f16 pairs, wave-uniform (SGPRs)
        unsigned ip[8];
        #pragma unroll
        for (int j = 0; j < 8; ++j)
            ip[j] = pack2h(bcast(item, 2 * j), bcast(item, 2 * j + 1));

        // online softmax over the 8 owned memories
        float Z = 0.f, o = 0.f;
        #pragma unroll
        for (int it = 0; it < 8; ++it) {
            const char* rbase = (const char*)rt + (ri[it] << 9);
            float q = 0.f;
            #pragma unroll
            for (int j = 0; j < 4; ++j) {
                uint2 u = *(const uint2*)(rbase + voff[j]);
                q = qdot2(u.x, ip[2 * j + 0], q);
                q = qdot2(u.y, ip[2 * j + 1], q);
            }
            float sc = dpp_sum16(q * hv[it]);   // item . (R @ h)
            float ex = __expf(sc);              // scores small: no max pass
            Z += ex;
            o += ex * tv[it];
        }
        Z += __shfl_xor(Z, 16);
        Z += __shfl_xor(Z, 32);
        o += __shfl_xor(o, 16);
        o += __shfl_xor(o, 32);
        o *= 1.f / Z;

        out_acc += (hop == 0) ? 2.f * o : o;    // faithful: result = o1 + 2*o0

        // item = (item + o) @ W.T ; W row e from LDS
        const float v = item + o;
        float nit = 0.f;
        const float4* wr = (const float4*)&ws[e * WPITCH];
        #pragma unroll
        for (int j = 0; j < 4; ++j) {
            float4 w = wr[j];
            nit += w.x * bcast(v, 4 * j + 0) + w.y * bcast(v, 4 * j + 1)
                 + w.z * bcast(v, 4 * j + 2) + w.w * bcast(v, 4 * j + 3);
        }
        item = nit;
    }

    if (lane < 16) out[n * DIM + e] = out_acc;
}

extern "C" void kernel_launch(void* const* d_in, const int* in_sizes, int n_in,
                              void* d_out, int out_size, void* d_ws, size_t ws_size,
                              hipStream_t stream) {
    const int*   nodes = (const int*)d_in[0];
    const int*   mh    = (const int*)d_in[1];
    const int*   mr    = (const int*)d_in[2];
    const int*   mt    = (const int*)d_in[3];
    const float* ent   = (const float*)d_in[4];
    const float* rel   = (const float*)d_in[5];
    const float* W     = (const float*)d_in[6];
    float*       out   = (float*)d_out;

    _Float16*       et  = (_Float16*)d_ws;                       // 3.2 MB
    unsigned short* rtg = (unsigned short*)((char*)d_ws + ET_BYTES); // 32 KB

    const int n4 = NE * DIM / 4;              // 400000 float4s
    prep_kernel<<<NB_ET + 4, 256, 0, stream>>>(ent, rel, et, rtg, n4);

    dim3 grid(NNODES / 4);   // 1 wave per node, 4 nodes per 256-thread block
    dim3 block(256);
    ripple_kernel<<<grid, block, 0, stream>>>(nodes, mh, mr, mt, et, rtg, W, out);
}